// Round 16
// baseline (300.541 us; speedup 1.0000x reference)
//
#include <hip/hip_runtime.h>

#define S_LEN 2048
#define DMODEL 1024
#define NH 16
#define NKVH 4
#define DKH 64
#define KVD 256
#define SCALE_LOG2E 0.18033688f  // (1/sqrt(64)) * log2(e)

typedef __bf16 bf16;
typedef bf16  bf16x8 __attribute__((ext_vector_type(8)));
typedef bf16  bf16x4 __attribute__((ext_vector_type(4)));
typedef float f32x4  __attribute__((ext_vector_type(4)));
typedef bf16x8 bf16x8_a __attribute__((may_alias));
typedef bf16x4 bf16x4_a __attribute__((may_alias));
typedef float f32x4g __attribute__((ext_vector_type(4), may_alias));

#define VWAIT(N)                                             \
    do {                                                     \
        asm volatile("s_waitcnt vmcnt(" #N ")" ::: "memory");\
        __builtin_amdgcn_sched_barrier(0);                   \
    } while (0)

#define LGKM0_BARRIER()                                       \
    do {                                                      \
        asm volatile("s_waitcnt lgkmcnt(0)" ::: "memory");    \
        __builtin_amdgcn_sched_barrier(0);                    \
        __builtin_amdgcn_s_barrier();                         \
        __builtin_amdgcn_sched_barrier(0);                    \
    } while (0)

__device__ __forceinline__ void gll16(const bf16* g, bf16* l) {
    __builtin_amdgcn_global_load_lds(
        (const __attribute__((address_space(1))) void*)g,
        (__attribute__((address_space(3))) void*)l, 16, 0, 0);
}

// ---------------- fused fp32 -> bf16 casts ----------------
__global__ __launch_bounds__(256) void cast3_bf16(const float* __restrict__ a,
                                                  const float* __restrict__ b,
                                                  const float* __restrict__ c,
                                                  bf16* __restrict__ oa, bf16* __restrict__ ob,
                                                  bf16* __restrict__ oc, int n4) {
    const float* src = blockIdx.y == 0 ? a : blockIdx.y == 1 ? b : c;
    bf16* dst = blockIdx.y == 0 ? oa : blockIdx.y == 1 ? ob : oc;
    int stride = gridDim.x * blockDim.x;
    for (int i = blockIdx.x * blockDim.x + threadIdx.x; i < n4; i += stride) {
        f32x4g v = ((const f32x4g*)src)[i];
        bf16x4 o;
        o[0] = (bf16)v[0]; o[1] = (bf16)v[1]; o[2] = (bf16)v[2]; o[3] = (bf16)v[3];
        ((bf16x4*)dst)[i] = o;
    }
}

__global__ __launch_bounds__(256) void cast2_bf16(const float* __restrict__ a,
                                                  const float* __restrict__ b,
                                                  bf16* __restrict__ oa, bf16* __restrict__ ob,
                                                  int n4) {
    const float* src = blockIdx.y == 0 ? a : b;
    bf16* dst = blockIdx.y == 0 ? oa : ob;
    int stride = gridDim.x * blockDim.x;
    for (int i = blockIdx.x * blockDim.x + threadIdx.x; i < n4; i += stride) {
        f32x4g v = ((const f32x4g*)src)[i];
        bf16x4 o;
        o[0] = (bf16)v[0]; o[1] = (bf16)v[1]; o[2] = (bf16)v[2]; o[3] = (bf16)v[3];
        ((bf16x4*)dst)[i] = o;
    }
}

// ---------------- NT GEMM: C[m][n] = sum_k A[m][k]*Bw[n][k] + bias[n] ----------------
template <int OUTF32>
__global__ __launch_bounds__(256) void gemm_bt(const bf16* __restrict__ A,
                                               const bf16* __restrict__ Bw,
                                               const float* __restrict__ bias,
                                               void* __restrict__ Cout,
                                               int M, int N, int K) {
    __shared__ bf16 As[4096];  // 128 x 32
    __shared__ bf16 Bs[4096];
    const int bm = blockIdx.x, bn = blockIdx.y;
    const int tid = threadIdx.x, wave = tid >> 6, lane = tid & 63;
    const int l15 = lane & 15, lhi = lane >> 4;
    const int wr = (wave >> 1) * 64, wc = (wave & 1) * 64;
    f32x4 acc[4][4] = {};
    const size_t arow0 = (size_t)bm * 128 * K;
    const size_t brow0 = (size_t)bn * 128 * K;

    for (int kt = 0; kt < K; kt += 32) {
#pragma unroll
        for (int i = 0; i < 2; ++i) {
            int base = i * 2048 + wave * 512;
            int flat = base + lane * 8;
            int r = flat >> 5, c = flat & 31;
            gll16(A + arow0 + (size_t)r * K + kt + c, &As[base]);
            gll16(Bw + brow0 + (size_t)r * K + kt + c, &Bs[base]);
        }
        __syncthreads();
        bf16x8 af[4], bfr[4];
#pragma unroll
        for (int mi = 0; mi < 4; ++mi)
            af[mi] = *(const bf16x8_a*)&As[(wr + mi * 16 + l15) * 32 + lhi * 8];
#pragma unroll
        for (int ni = 0; ni < 4; ++ni)
            bfr[ni] = *(const bf16x8_a*)&Bs[(wc + ni * 16 + l15) * 32 + lhi * 8];
#pragma unroll
        for (int mi = 0; mi < 4; ++mi)
#pragma unroll
            for (int ni = 0; ni < 4; ++ni)
                acc[mi][ni] = __builtin_amdgcn_mfma_f32_16x16x32_bf16(
                    af[mi], bfr[ni], acc[mi][ni], 0, 0, 0);
        __syncthreads();
    }
#pragma unroll
    for (int mi = 0; mi < 4; ++mi)
#pragma unroll
        for (int ni = 0; ni < 4; ++ni)
#pragma unroll
            for (int j = 0; j < 4; ++j) {
                int row = bm * 128 + wr + mi * 16 + lhi * 4 + j;
                int col = bn * 128 + wc + ni * 16 + l15;
                float v = acc[mi][ni][j] + bias[col];
                if (OUTF32)
                    ((float*)Cout)[(size_t)row * N + col] = v;
                else
                    ((bf16*)Cout)[(size_t)row * N + col] = (bf16)v;
            }
}

// ---------------- V transpose: Vp[b*2048+s][g*64+d] -> VT[b][g][d][s] ----------------
__global__ __launch_bounds__(256) void vtrans(const bf16* __restrict__ V,
                                              bf16* __restrict__ VT) {
    __shared__ bf16 t[64][65];
    const int s0 = blockIdx.x * 64;
    const int bg = blockIdx.y;
    const int b = bg >> 2, g = bg & 3;
#pragma unroll
    for (int i = 0; i < 16; ++i) {
        int flat = threadIdx.x + i * 256;
        int r = flat >> 6, c = flat & 63;
        t[c][r] = V[(size_t)(b * S_LEN + s0 + r) * KVD + g * DKH + c];
    }
    __syncthreads();
#pragma unroll
    for (int i = 0; i < 16; ++i) {
        int flat = threadIdx.x + i * 256;
        int d = flat >> 6, si = flat & 63;
        VT[((size_t)bg * DKH + d) * S_LEN + s0 + si] = t[d][si];
    }
}

// ---------------- merged attention v6: 128-key chunks (half the barriers) ----------------
// grid 2048 (XCD-swizzled) = bh(32) x qt(64: 32 q-rows); block 512 = 8 waves (2 wq x 4 wk).
// Pass A: 16 chunks x 128 keys, K ring-4 of 16KB, depth-2 prefetch.
// Pass B: 16 chunks, K ring-2 + V ring-2 (16KB each) + single Pb [32q][128k];
// per chunk: bar1 (K/V ready) -> QK(4 MFMA) -> Pb -> lgkm-bar2 -> stores + PV(4 MFMA).
__global__ __launch_bounds__(512, 4) void attn_all(const bf16* __restrict__ Qp,
                                                   const bf16* __restrict__ Kp,
                                                   const bf16* __restrict__ VT,
                                                   float* __restrict__ attn_out,
                                                   bf16* __restrict__ ctx) {
    __shared__ bf16 KV[4][8192];  // 64 KB: pass A = K ring4; pass B = K{0,1}, V{2,3}
    __shared__ bf16 Pb[4096];     // 8 KB [32 q][128 k] bf16 swizzled; head = red[128] f32
    const int raw = blockIdx.x;
    const int wg = (raw & 7) * 256 + (raw >> 3);  // 2048 % 8 == 0: bijective
    const int bh = wg >> 6;
    const int qt = wg & 63;
    const int h = bh & (NH - 1), b = bh >> 4, g = h >> 2;
    const int tid = threadIdx.x, wave = tid >> 6, lane = tid & 63;
    const int l15 = lane & 15, lhi = lane >> 4;
    const int wq = wave >> 2, wk = wave & 3;  // wk doubles as dv-tile in PV
    const int qrow0 = qt * 32;
    const int sw = (l15 & 7) << 4;

    const bf16* qb =
        Qp + (size_t)(b * S_LEN + qrow0 + wq * 16 + l15) * DMODEL + h * DKH + lhi * 8;
    bf16x8 aq0 = *(const bf16x8_a*)qb;
    bf16x8 aq1 = *(const bf16x8_a*)(qb + 32);

    // K staging geometry: thread -> (row tid>>3 within 64-row half, 16B slot tid&7),
    // source col pre-swizzled; round r covers rows r*64..r*64+63 of a 128-row chunk.
    const int srow = tid >> 3;
    const int scc = (tid & 7) ^ (srow & 7);
    const bf16* ksrc = Kp + (size_t)(b * S_LEN + srow) * KVD + g * DKH + scc * 8;
    // V staging geometry: round r covers dv rows r*32..r*32+31; thread -> row tid>>4,
    // 16B slot (lane&15) pre-swizzled by row&7.
    const int vrow = tid >> 4;  // 0..31
    const bf16* vsrc = VT + ((size_t)(b * NKVH + g) * DKH + vrow) * S_LEN +
                       ((lane & 15) ^ (vrow & 7)) * 8;

    // ================= pass A: denominators, 16 chunks x 128 keys, ring-4 =================
    gll16(ksrc, &KV[0][wave * 512]);
    gll16(ksrc + (size_t)64 * KVD, &KV[0][4096 + wave * 512]);
    gll16(ksrc + (size_t)128 * KVD, &KV[1][wave * 512]);
    gll16(ksrc + (size_t)192 * KVD, &KV[1][4096 + wave * 512]);
    float lsum = 0.f;
    for (int c = 0; c < 16; ++c) {
        if (c < 14) {
            const bf16* s = ksrc + (size_t)((c + 2) * 128) * KVD;
            gll16(s, &KV[(c + 2) & 3][wave * 512]);
            gll16(s + (size_t)64 * KVD, &KV[(c + 2) & 3][4096 + wave * 512]);
        }
        if (c < 14) { VWAIT(4); } else if (c == 14) { VWAIT(2); } else { VWAIT(0); }
        __builtin_amdgcn_s_barrier();
        const char* kc = (const char*)&KV[c & 3][0];
        __builtin_amdgcn_s_setprio(1);
        f32x4 a0 = {0.f, 0.f, 0.f, 0.f}, a1 = {0.f, 0.f, 0.f, 0.f};
        {
            const int rb = (wk * 32 + l15) * 128;
            bf16x8 k0 = *(const bf16x8_a*)(kc + rb + ((lhi * 16) ^ sw));
            bf16x8 k1 = *(const bf16x8_a*)(kc + rb + ((lhi * 16 + 64) ^ sw));
            a0 = __builtin_amdgcn_mfma_f32_16x16x32_bf16(k0, aq0, a0, 0, 0, 0);
            a0 = __builtin_amdgcn_mfma_f32_16x16x32_bf16(k1, aq1, a0, 0, 0, 0);
        }
        {
            const int rb = (wk * 32 + 16 + l15) * 128;
            bf16x8 k0 = *(const bf16x8_a*)(kc + rb + ((lhi * 16) ^ sw));
            bf16x8 k1 = *(const bf16x8_a*)(kc + rb + ((lhi * 16 + 64) ^ sw));
            a1 = __builtin_amdgcn_mfma_f32_16x16x32_bf16(k0, aq0, a1, 0, 0, 0);
            a1 = __builtin_amdgcn_mfma_f32_16x16x32_bf16(k1, aq1, a1, 0, 0, 0);
        }
        __builtin_amdgcn_s_setprio(0);
        lsum += __builtin_exp2f(a0[0] * SCALE_LOG2E) + __builtin_exp2f(a0[1] * SCALE_LOG2E) +
                __builtin_exp2f(a0[2] * SCALE_LOG2E) + __builtin_exp2f(a0[3] * SCALE_LOG2E) +
                __builtin_exp2f(a1[0] * SCALE_LOG2E) + __builtin_exp2f(a1[1] * SCALE_LOG2E) +
                __builtin_exp2f(a1[2] * SCALE_LOG2E) + __builtin_exp2f(a1[3] * SCALE_LOG2E);
    }
    lsum += __shfl_xor(lsum, 16, 64);
    lsum += __shfl_xor(lsum, 32, 64);

    float* red = (float*)&Pb[0];  // 512 B scratch in Pb head
    LGKM0_BARRIER();              // pass A KV reads done (restageable)
    if (lane < 16) red[wave * 16 + lane] = lsum;
    // pass B prologue: K(0)->KV[0], V(0)->KV[2]
    gll16(ksrc, &KV[0][wave * 512]);
    gll16(ksrc + (size_t)64 * KVD, &KV[0][4096 + wave * 512]);
    gll16(vsrc, &KV[2][wave * 512]);
    gll16(vsrc + (size_t)32 * S_LEN, &KV[2][4096 + wave * 512]);
    LGKM0_BARRIER();  // red visible
    float lt = red[(wq * 4 + 0) * 16 + l15] + red[(wq * 4 + 1) * 16 + l15] +
               red[(wq * 4 + 2) * 16 + l15] + red[(wq * 4 + 3) * 16 + l15];
    const float nlog = -__builtin_log2f(lt);  // normalize inside the exponent
    LGKM0_BARRIER();  // red reads complete before Pb reuse

    // ================= pass B: probs + PV, 16 chunks x 128 keys =================
    f32x4 cacc = {0.f, 0.f, 0.f, 0.f};
    float* arow = attn_out + ((size_t)bh * S_LEN + qrow0) * S_LEN;
    char* pbb = (char*)&Pb[0];
    const int ql = wq * 16 + l15;  // q-row this lane produces
    const int pbw0 = ql * 256 + ((wk * 64 + lhi * 8) ^ sw);
    const int pbw1 = ql * 256 + ((wk * 64 + 32 + lhi * 8) ^ sw);
    const int strow = tid >> 4;  // 0..31 store row
    const int stslot = tid & 15;
    const int pbr0 = strow * 256 + ((stslot * 8) ^ ((strow & 7) << 4));
    const int pbr1 = strow * 256 + ((128 + stslot * 8) ^ ((strow & 7) << 4));
    float* gst = arow + (size_t)strow * S_LEN + stslot * 4;

    for (int c = 0; c < 16; ++c) {
        // outstanding at head: stage(c)4 [oldest], store(c-1)2 -> VWAIT(2) keeps stores
        if (c == 0) { VWAIT(0); } else { VWAIT(2); }
        __builtin_amdgcn_s_barrier();  // bar1: K(c), V(c) resident
        if (c < 15) {
            const bf16* s = ksrc + (size_t)((c + 1) * 128) * KVD;
            gll16(s, &KV[(c + 1) & 1][wave * 512]);
            gll16(s + (size_t)64 * KVD, &KV[(c + 1) & 1][4096 + wave * 512]);
            const bf16* v = vsrc + (c + 1) * 128;
            gll16(v, &KV[2 + ((c + 1) & 1)][wave * 512]);
            gll16(v + (size_t)32 * S_LEN, &KV[2 + ((c + 1) & 1)][4096 + wave * 512]);
            __builtin_amdgcn_sched_barrier(0);
        }
        // QK(c): two 16-key subtiles for keys wk*32 .. wk*32+31
        const char* kc = (const char*)&KV[c & 1][0];
        __builtin_amdgcn_s_setprio(1);
        f32x4 a0 = {0.f, 0.f, 0.f, 0.f}, a1 = {0.f, 0.f, 0.f, 0.f};
        {
            const int rb = (wk * 32 + l15) * 128;
            bf16x8 k0 = *(const bf16x8_a*)(kc + rb + ((lhi * 16) ^ sw));
            bf16x8 k1 = *(const bf16x8_a*)(kc + rb + ((lhi * 16 + 64) ^ sw));
            a0 = __builtin_amdgcn_mfma_f32_16x16x32_bf16(k0, aq0, a0, 0, 0, 0);
            a0 = __builtin_amdgcn_mfma_f32_16x16x32_bf16(k1, aq1, a0, 0, 0, 0);
        }
        {
            const int rb = (wk * 32 + 16 + l15) * 128;
            bf16x8 k0 = *(const bf16x8_a*)(kc + rb + ((lhi * 16) ^ sw));
            bf16x8 k1 = *(const bf16x8_a*)(kc + rb + ((lhi * 16 + 64) ^ sw));
            a1 = __builtin_amdgcn_mfma_f32_16x16x32_bf16(k0, aq0, a1, 0, 0, 0);
            a1 = __builtin_amdgcn_mfma_f32_16x16x32_bf16(k1, aq1, a1, 0, 0, 0);
        }
        __builtin_amdgcn_s_setprio(0);
        // P(c) = exp2(a*s + nlog), bf16 -> Pb (normalized)
        bf16x4 p0, p1;
#pragma unroll
        for (int j = 0; j < 4; ++j) {
            p0[j] = (bf16)__builtin_exp2f(__builtin_fmaf(a0[j], SCALE_LOG2E, nlog));
            p1[j] = (bf16)__builtin_exp2f(__builtin_fmaf(a1[j], SCALE_LOG2E, nlog));
        }
        *(bf16x4_a*)(pbb + pbw0) = p0;
        *(bf16x4_a*)(pbb + pbw1) = p1;
        LGKM0_BARRIER();  // bar2: P(c) visible block-wide
        // prob store: 2 x (re-read Pb, widen, 256B-contig per 16-lane group)
        {
            bf16x4 q0 = *(const bf16x4_a*)(pbb + pbr0);
            bf16x4 q1 = *(const bf16x4_a*)(pbb + pbr1);
            f32x4 f0, f1;
#pragma unroll
            for (int j = 0; j < 4; ++j) { f0[j] = (float)q0[j]; f1[j] = (float)q1[j]; }
            *(f32x4g*)(gst + c * 128) = f0;
            *(f32x4g*)(gst + c * 128 + 64) = f1;
        }
        // PV(c): 4 k-slabs of 32
        const char* vc = (const char*)&KV[2 + (c & 1)][0];
        const int vb = (wk * 16 + l15) * 256;
        __builtin_amdgcn_s_setprio(1);
#pragma unroll
        for (int ks = 0; ks < 4; ++ks) {
            bf16x8 ap = *(const bf16x8_a*)(pbb + ql * 256 + ((ks * 64 + lhi * 16) ^ sw));
            bf16x8 vv = *(const bf16x8_a*)(vc + vb + ((ks * 64 + lhi * 16) ^ sw));
            cacc = __builtin_amdgcn_mfma_f32_16x16x32_bf16(ap, vv, cacc, 0, 0, 0);
        }
        __builtin_amdgcn_s_setprio(0);
    }
    // ctx write: q = qrow0 + wq*16 + lhi*4 + j, dv = h*64 + wk*16 + l15 (P pre-normalized)
#pragma unroll
    for (int j = 0; j < 4; ++j) {
        int row = qrow0 + wq * 16 + lhi * 4 + j;
        ctx[(size_t)(b * S_LEN + row) * DMODEL + h * DKH + wk * 16 + l15] = (bf16)cacc[j];
    }
}

extern "C" void kernel_launch(void* const* d_in, const int* in_sizes, int n_in,
                              void* d_out, int out_size, void* d_ws, size_t ws_size,
                              hipStream_t stream) {
    const float* query = (const float*)d_in[0];
    const float* key_i = (const float*)d_in[1];
    const float* value = (const float*)d_in[2];
    const float* Wq = (const float*)d_in[3];
    const float* bq = (const float*)d_in[4];
    const float* Wk = (const float*)d_in[5];
    const float* bk = (const float*)d_in[6];
    const float* Wv = (const float*)d_in[7];
    const float* bv = (const float*)d_in[8];
    const float* Wo = (const float*)d_in[9];
    const float* bo = (const float*)d_in[10];

    char* ws = (char*)d_ws;
    bf16* qx = (bf16*)(ws + 0);
    bf16* kx = (bf16*)(ws + ((size_t)8 << 20));
    bf16* vx = (bf16*)(ws + ((size_t)16 << 20));
    bf16* wqx = (bf16*)(ws + ((size_t)32 << 20));
    bf16* wkx = (bf16*)(ws + ((size_t)34 << 20));
    bf16* wvx = (bf16*)(ws + ((size_t)34 << 20) + ((size_t)512 << 10));
    bf16* wox = (bf16*)(ws + ((size_t)35 << 20));
    bf16* Qp = (bf16*)(ws + ((size_t)37 << 20));
    bf16* Kp = (bf16*)(ws + ((size_t)45 << 20));
    bf16* Vp = (bf16*)(ws + ((size_t)47 << 20));
    bf16* VT = (bf16*)(ws + ((size_t)49 << 20));
    bf16* ctxb = (bf16*)(ws + ((size_t)51 << 20));

    const int BS = 2 * S_LEN;  // 4096 rows

    cast3_bf16<<<dim3(1024, 3), 256, 0, stream>>>(query, key_i, value, qx, kx, vx,
                                                  BS * DMODEL / 4);
    cast2_bf16<<<dim3(1024, 2), 256, 0, stream>>>(Wq, Wo, wqx, wox, DMODEL * DMODEL / 4);
    cast2_bf16<<<dim3(256, 2), 256, 0, stream>>>(Wk, Wv, wkx, wvx, KVD * DMODEL / 4);

    gemm_bt<0><<<dim3(32, 8), 256, 0, stream>>>(qx, wqx, bq, Qp, BS, DMODEL, DMODEL);
    gemm_bt<0><<<dim3(32, 2), 256, 0, stream>>>(kx, wkx, bk, Kp, BS, KVD, DMODEL);
    gemm_bt<0><<<dim3(32, 2), 256, 0, stream>>>(vx, wvx, bv, Vp, BS, KVD, DMODEL);

    vtrans<<<dim3(32, 8), 256, 0, stream>>>(Vp, VT);

    float* attn_out = (float*)d_out + (size_t)BS * DMODEL;
    attn_all<<<2048, 512, 0, stream>>>(Qp, Kp, VT, attn_out, ctxb);

    gemm_bt<1><<<dim3(32, 8), 256, 0, stream>>>(ctxb, wox, bo, (float*)d_out, BS, DMODEL, DMODEL);
}